// Round 1
// baseline (2678.115 us; speedup 1.0000x reference)
//
#include <hip/hip_runtime.h>
#include <float.h>

// Sparsemax attention, fp32, one wave (64 lanes) per query row.
// B=64, Lq=Lk=1024, D=64.  d_out = out[B,Lq,D] ++ attn[B,Lq,Lk], fp32.
//
// Per row: lane L holds scores for keys j = L + 64*t, t=0..15, in registers.
// tau via Michelot's exact iteration seeded with thr = rowmax - 1 (bound:
// tau >= max-1 since the top entry contributes at most 1 to the simplex sum).
// PV is done only over the sparse support via ballot + shfl (support ~5-30).

#define BATCH    64
#define SEQ_Q    1024
#define SEQ_K    1024
#define DHEAD    64
#define NTHREADS 256
#define ROWS_PER_BLOCK 4   // 4 waves, 1 row each

// ---- mask dtype detector: 1-byte bools vs int32 0/1 -----------------------
// If mask is int32 little-endian 0/1, every byte at offset %4 != 0 is zero.
// If mask is 1-byte bools (~50% ones), we find a nonzero almost immediately.
__global__ void detect_mask_fmt(const unsigned char* __restrict__ m,
                                int* __restrict__ flag) {
    __shared__ int s_found;
    if (threadIdx.x == 0) s_found = 0;
    __syncthreads();
    int found = 0;
    for (int o = threadIdx.x; o < 65536; o += NTHREADS) {
        if ((o & 3) != 0 && m[o] != 0) found = 1;
    }
    if (found) atomicOr(&s_found, 1);
    __syncthreads();
    if (threadIdx.x == 0) *flag = s_found;   // 1 => bytes, 0 => int32
}

__global__ void sparse_attn(const float* __restrict__ q,
                            const float* __restrict__ k,
                            const float* __restrict__ v,
                            const void* __restrict__ mask,
                            const int* __restrict__ fmt_flag,
                            float* __restrict__ out,
                            float* __restrict__ attn) {
    const int lane = threadIdx.x & 63;
    const int wave = threadIdx.x >> 6;
    const int row  = blockIdx.x * ROWS_PER_BLOCK + wave;   // [0, B*Lq)
    const int b    = row >> 10;
    const size_t koff = (size_t)b * SEQ_K * DHEAD;
    const size_t moff = (size_t)row * SEQ_K;
    const int mask_is_byte = fmt_flag ? *fmt_flag : 1;

    // q row -> registers, pre-scaled by 1/TEMPERATURE (= 1/8)
    float4 qv[16];
    {
        const float4* q4 = (const float4*)(q + (size_t)row * DHEAD);
        #pragma unroll
        for (int i = 0; i < 16; ++i) {
            float4 t = q4[i];
            qv[i].x = t.x * 0.125f; qv[i].y = t.y * 0.125f;
            qv[i].z = t.z * 0.125f; qv[i].w = t.w * 0.125f;
        }
    }

    // mask values for this lane's 16 key positions (uniform branch)
    int mvals[16];
    if (mask_is_byte) {
        const unsigned char* m8 = (const unsigned char*)mask + moff;
        #pragma unroll
        for (int t = 0; t < 16; ++t) mvals[t] = m8[lane + 64 * t];
    } else {
        const int* m32 = (const int*)mask + moff;
        #pragma unroll
        for (int t = 0; t < 16; ++t) mvals[t] = m32[lane + 64 * t];
    }

    // ---- phase 1: scores s_j = (q/8) . k_j, masked -> -FLT_MAX ------------
    float s[16];
    float mx = -FLT_MAX;
    #pragma unroll 2
    for (int t = 0; t < 16; ++t) {
        const float4* k4 =
            (const float4*)(k + koff + (size_t)(lane + 64 * t) * DHEAD);
        float a0 = 0.f, a1 = 0.f, a2 = 0.f, a3 = 0.f;
        #pragma unroll
        for (int i = 0; i < 16; ++i) {
            float4 kv = k4[i];
            a0 = fmaf(qv[i].x, kv.x, a0);
            a1 = fmaf(qv[i].y, kv.y, a1);
            a2 = fmaf(qv[i].z, kv.z, a2);
            a3 = fmaf(qv[i].w, kv.w, a3);
        }
        float acc = (a0 + a1) + (a2 + a3);
        if (mvals[t]) acc = -FLT_MAX;
        s[t] = acc;
        mx = fmaxf(mx, acc);
    }

    // wave max
    #pragma unroll
    for (int off = 32; off >= 1; off >>= 1)
        mx = fmaxf(mx, __shfl_xor(mx, off, 64));

    float* attn_row = attn + moff;

    // fully masked row -> all zeros (matches reference post-zeroing)
    if (mx <= -FLT_MAX) {
        #pragma unroll
        for (int t = 0; t < 16; ++t) attn_row[lane + 64 * t] = 0.f;
        out[(size_t)row * DHEAD + lane] = 0.f;
        return;
    }

    // ---- phase 2: Michelot iteration for exact sparsemax tau --------------
    // Invariant: active set A = {s > thr} always contains the true support.
    // thr = mx - 1 is a valid seed (tau* >= mx - 1). tau is non-decreasing,
    // A shrinks strictly until fixed point; stop when |A| stops changing.
    float thr = mx - 1.0f;
    float tau = 0.0f;
    int cnt_prev = -1;
    for (int it = 0; it < 64; ++it) {
        float lsum = 0.f;
        int   lcnt = 0;
        #pragma unroll
        for (int t = 0; t < 16; ++t) {
            if (s[t] > thr) { lsum += s[t]; lcnt++; }
        }
        #pragma unroll
        for (int off = 32; off >= 1; off >>= 1) {
            lsum += __shfl_xor(lsum, off, 64);
            lcnt += __shfl_xor(lcnt, off, 64);
        }
        tau = (lsum - 1.0f) / (float)lcnt;
        if (lcnt == cnt_prev) break;
        cnt_prev = lcnt;
        thr = tau;
    }

    // ---- phase 3: attn = max(s - tau, 0); sparse PV over the support ------
    float p[16];
    float oacc = 0.f;
    const float* vbase = v + koff;
    #pragma unroll
    for (int t = 0; t < 16; ++t) {
        float pv = s[t] - tau;
        pv = pv > 0.f ? pv : 0.f;
        p[t] = pv;
        attn_row[lane + 64 * t] = pv;
        unsigned long long mball = __ballot(pv > 0.f);   // wave-uniform
        while (mball) {
            int src = __ffsll(mball) - 1;
            mball &= mball - 1;
            float pj = __shfl(p[t], src);
            const float* vrow = vbase + (size_t)(src + 64 * t) * DHEAD;
            oacc = fmaf(pj, vrow[lane], oacc);
        }
    }
    out[(size_t)row * DHEAD + lane] = oacc;
}

extern "C" void kernel_launch(void* const* d_in, const int* in_sizes, int n_in,
                              void* d_out, int out_size, void* d_ws, size_t ws_size,
                              hipStream_t stream) {
    const float* q = (const float*)d_in[0];
    const float* k = (const float*)d_in[1];
    const float* v = (const float*)d_in[2];
    const void*  m = d_in[3];

    float* out  = (float*)d_out;                          // [B, Lq, D]
    float* attn = out + (size_t)BATCH * SEQ_Q * DHEAD;    // [B, Lq, Lk]

    int* flag = nullptr;
    if (ws_size >= sizeof(int)) {
        flag = (int*)d_ws;
        detect_mask_fmt<<<1, NTHREADS, 0, stream>>>((const unsigned char*)m, flag);
    }
    sparse_attn<<<(BATCH * SEQ_Q) / ROWS_PER_BLOCK, NTHREADS, 0, stream>>>(
        q, k, v, m, flag, out, attn);
}

// Round 2
// 719.653 us; speedup vs baseline: 3.7214x; 3.7214x over previous
//
#include <hip/hip_runtime.h>
#include <float.h>

// Sparsemax attention, fp32 in/out. B=64, Lq=Lk=1024, D=64.
// d_out = out[B,Lq,D] ++ attn[B,Lq,Lk], fp32.
//
// Two-kernel plan:
//   A) score_kernel: S = (Q/8)·K^T via bf16 MFMA with hi/lo split (3 passes,
//      ~fp32 accuracy). K-tile staged in LDS (XOR-swizzled, 2-way banks = free).
//      Raw scores written fp32 into the attn buffer (written anyway).
//   B) sparsemax_pv: wave per row; coalesced float4 score + mask loads; exact
//      Michelot tau iteration; attn = relu(s-tau) written back coalesced;
//      sparse PV via ballot+shfl over the support (~5-30 keys/row).

#define BATCH    64
#define SEQQ     1024
#define SEQK     1024
#define DHEAD    64

typedef short short8 __attribute__((ext_vector_type(8)));
typedef float f32x4  __attribute__((ext_vector_type(4)));

__device__ __forceinline__ unsigned short bf16_rne(float f) {
    unsigned u = __float_as_uint(f);
    u += 0x7fffu + ((u >> 16) & 1u);
    return (unsigned short)(u >> 16);
}

__device__ __forceinline__ void cvt_hilo8(const float* fv, float scale,
                                          short8* hi, short8* lo) {
    #pragma unroll
    for (int j = 0; j < 8; ++j) {
        float f = fv[j] * scale;
        unsigned short hb = bf16_rne(f);
        float hf = __uint_as_float((unsigned)hb << 16);
        (*hi)[j] = (short)hb;
        (*lo)[j] = (short)bf16_rne(f - hf);
    }
}

// ---- mask dtype detector: 1-byte bools vs int32 0/1 (worked in R1) --------
__global__ void detect_mask_fmt(const unsigned char* __restrict__ m,
                                int* __restrict__ flag) {
    __shared__ int s_found;
    if (threadIdx.x == 0) s_found = 0;
    __syncthreads();
    int found = 0;
    for (int o = threadIdx.x; o < 65536; o += 256) {
        if ((o & 3) != 0 && m[o] != 0) found = 1;
    }
    if (found) atomicOr(&s_found, 1);
    __syncthreads();
    if (threadIdx.x == 0) *flag = s_found;   // 1 => bytes, 0 => int32
}

// ---- kernel A: raw scores via MFMA (hi/lo bf16 split) ---------------------
// grid (kt=8, qt=16, b=64); block 256 = 4 waves; wave w -> 16 q-rows strip.
__global__ __launch_bounds__(256) void score_kernel(
        const float* __restrict__ q, const float* __restrict__ k,
        float* __restrict__ attn) {
    const int lane = threadIdx.x & 63;
    const int wave = threadIdx.x >> 6;
    const int quad = lane >> 4;
    const int l15  = lane & 15;
    const int kt = blockIdx.x, qt = blockIdx.y, b = blockIdx.z;

    // [hl][key(128)][d(64)] ushort, 16B-group XOR-swizzled on d-block
    __shared__ unsigned short klds[2 * 128 * 64];

    const float* kbase = k + ((size_t)b * SEQK + kt * 128) * DHEAD;
    #pragma unroll
    for (int it = 0; it < 4; ++it) {
        int e   = threadIdx.x + 256 * it;    // 1024 groups of 8 elems
        int key = e >> 3, db = e & 7;
        const float4* src = (const float4*)(kbase + key * DHEAD + db * 8);
        float4 f0 = src[0], f1 = src[1];
        float fv[8] = {f0.x, f0.y, f0.z, f0.w, f1.x, f1.y, f1.z, f1.w};
        short8 hi, lo;
        cvt_hilo8(fv, 1.0f, &hi, &lo);
        int off = key * 64 + ((db ^ (key & 7)) * 8);   // ushort units
        *(short8*)(klds + off)        = hi;
        *(short8*)(klds + 8192 + off) = lo;
    }
    __syncthreads();

    // A-frags: lane holds Q[qbase + l15][kc*32 + quad*8 + j], scaled by 1/8
    const float* qrow =
        q + ((size_t)b * SEQQ + qt * 64 + wave * 16 + l15) * DHEAD;
    short8 a_hi[2], a_lo[2];
    #pragma unroll
    for (int kc = 0; kc < 2; ++kc) {
        const float4* src = (const float4*)(qrow + kc * 32 + quad * 8);
        float4 f0 = src[0], f1 = src[1];
        float fv[8] = {f0.x, f0.y, f0.z, f0.w, f1.x, f1.y, f1.z, f1.w};
        cvt_hilo8(fv, 0.125f, &a_hi[kc], &a_lo[kc]);
    }

    float* arow = attn + ((size_t)b * SEQQ + qt * 64 + wave * 16) * SEQK
                       + kt * 128;
    #pragma unroll
    for (int g = 0; g < 8; ++g) {
        int key = g * 16 + l15;
        short8 b_hi[2], b_lo[2];
        #pragma unroll
        for (int kc = 0; kc < 2; ++kc) {
            int db  = kc * 4 + quad;
            int off = key * 64 + ((db ^ (key & 7)) * 8);
            b_hi[kc] = *(const short8*)(klds + off);
            b_lo[kc] = *(const short8*)(klds + 8192 + off);
        }
        f32x4 acc = {0.f, 0.f, 0.f, 0.f};
        #pragma unroll
        for (int kc = 0; kc < 2; ++kc) {
            acc = __builtin_amdgcn_mfma_f32_16x16x32_bf16(a_hi[kc], b_hi[kc], acc, 0, 0, 0);
            acc = __builtin_amdgcn_mfma_f32_16x16x32_bf16(a_lo[kc], b_hi[kc], acc, 0, 0, 0);
            acc = __builtin_amdgcn_mfma_f32_16x16x32_bf16(a_hi[kc], b_lo[kc], acc, 0, 0, 0);
        }
        // C layout: col = l15, row = quad*4 + r
        #pragma unroll
        for (int r = 0; r < 4; ++r)
            arow[(size_t)(quad * 4 + r) * SEQK + g * 16 + l15] = acc[r];
    }
}

// ---- kernel B: sparsemax + sparse PV, one wave per row --------------------
__global__ __launch_bounds__(256) void sparsemax_pv(
        const float* __restrict__ v, const void* __restrict__ mask,
        const int* __restrict__ fmt_flag,
        float* __restrict__ out, float* __restrict__ attn) {
    const int lane = threadIdx.x & 63;
    const int wave = threadIdx.x >> 6;
    const int row  = blockIdx.x * 4 + wave;
    const int b    = row >> 10;
    float* arow = attn + (size_t)row * SEQK;
    const int mask_is_byte = fmt_flag ? *fmt_flag : 1;

    // lane holds keys 4*(lane+64t)+c, t=0..3, c=0..3 (coalesced float4)
    float s[16];
    #pragma unroll
    for (int t = 0; t < 4; ++t) {
        float4 f = ((const float4*)arow)[lane + 64 * t];
        s[4*t+0] = f.x; s[4*t+1] = f.y; s[4*t+2] = f.z; s[4*t+3] = f.w;
    }
    if (mask_is_byte) {
        const unsigned* m32 =
            (const unsigned*)((const unsigned char*)mask + (size_t)row * SEQK);
        #pragma unroll
        for (int t = 0; t < 4; ++t) {
            unsigned m = m32[lane + 64 * t];
            if (m & 0x000000ffu) s[4*t+0] = -FLT_MAX;
            if (m & 0x0000ff00u) s[4*t+1] = -FLT_MAX;
            if (m & 0x00ff0000u) s[4*t+2] = -FLT_MAX;
            if (m & 0xff000000u) s[4*t+3] = -FLT_MAX;
        }
    } else {
        const int4* m4 = (const int4*)((const int*)mask + (size_t)row * SEQK);
        #pragma unroll
        for (int t = 0; t < 4; ++t) {
            int4 m = m4[lane + 64 * t];
            if (m.x) s[4*t+0] = -FLT_MAX;
            if (m.y) s[4*t+1] = -FLT_MAX;
            if (m.z) s[4*t+2] = -FLT_MAX;
            if (m.w) s[4*t+3] = -FLT_MAX;
        }
    }

    float mx = -FLT_MAX;
    #pragma unroll
    for (int i = 0; i < 16; ++i) mx = fmaxf(mx, s[i]);
    #pragma unroll
    for (int off = 32; off >= 1; off >>= 1)
        mx = fmaxf(mx, __shfl_xor(mx, off, 64));

    if (mx <= -FLT_MAX) {   // fully masked row -> zeros
        float4 z = {0.f, 0.f, 0.f, 0.f};
        #pragma unroll
        for (int t = 0; t < 4; ++t) ((float4*)arow)[lane + 64 * t] = z;
        out[(size_t)row * DHEAD + lane] = 0.f;
        return;
    }

    // Michelot: seed thr = mx-1 (tau* >= mx-1); A shrinks to exact support.
    float thr = mx - 1.0f, tau = 0.f;
    int cnt_prev = -1;
    for (int it = 0; it < 32; ++it) {
        float lsum = 0.f; int lcnt = 0;
        #pragma unroll
        for (int i = 0; i < 16; ++i)
            if (s[i] > thr) { lsum += s[i]; lcnt++; }
        #pragma unroll
        for (int off = 32; off >= 1; off >>= 1) {
            lsum += __shfl_xor(lsum, off, 64);
            lcnt += __shfl_xor(lcnt, off, 64);
        }
        tau = (lsum - 1.0f) / (float)lcnt;
        if (lcnt == cnt_prev) break;
        cnt_prev = lcnt;
        thr = tau;
    }

    float p[16];
    #pragma unroll
    for (int i = 0; i < 16; ++i) {
        float pv = s[i] - tau;
        p[i] = pv > 0.f ? pv : 0.f;
    }
    #pragma unroll
    for (int t = 0; t < 4; ++t) {
        float4 f = {p[4*t+0], p[4*t+1], p[4*t+2], p[4*t+3]};
        ((float4*)arow)[lane + 64 * t] = f;
    }

    // sparse PV: support is ~5-30 keys; v row loads are lane-contiguous
    const float* vbase = v + (size_t)b * SEQK * DHEAD;
    float oacc = 0.f;
    #pragma unroll
    for (int t = 0; t < 4; ++t) {
        #pragma unroll
        for (int c = 0; c < 4; ++c) {
            int i = 4 * t + c;
            unsigned long long mball = __ballot(p[i] > 0.f);
            while (mball) {
                int src = __ffsll(mball) - 1;
                mball &= mball - 1;
                float pj = __shfl(p[i], src);
                int key = 4 * (src + 64 * t) + c;
                oacc = fmaf(pj, vbase[(size_t)key * DHEAD + lane], oacc);
            }
        }
    }
    out[(size_t)row * DHEAD + lane] = oacc;
}

extern "C" void kernel_launch(void* const* d_in, const int* in_sizes, int n_in,
                              void* d_out, int out_size, void* d_ws, size_t ws_size,
                              hipStream_t stream) {
    const float* q = (const float*)d_in[0];
    const float* k = (const float*)d_in[1];
    const float* v = (const float*)d_in[2];
    const void*  m = d_in[3];

    float* out  = (float*)d_out;
    float* attn = out + (size_t)BATCH * SEQQ * DHEAD;

    int* flag = nullptr;
    if (ws_size >= sizeof(int)) {
        flag = (int*)d_ws;
        detect_mask_fmt<<<1, 256, 0, stream>>>((const unsigned char*)m, flag);
    }

    dim3 gridA(SEQK / 128, SEQQ / 64, BATCH);
    score_kernel<<<gridA, 256, 0, stream>>>(q, k, attn);

    sparsemax_pv<<<(BATCH * SEQQ) / 4, 256, 0, stream>>>(v, m, flag, out, attn);
}